// Round 5
// baseline (266.172 us; speedup 1.0000x reference)
//
#include <hip/hip_runtime.h>
#include <math.h>

#define B_  2
#define T_  2048
#define D_  1024
#define H_  16
#define HD_ 64

typedef float    f32x4  __attribute__((ext_vector_type(4)));
typedef _Float16 half8  __attribute__((ext_vector_type(8)));
typedef _Float16 half4v __attribute__((ext_vector_type(4)));

#define GLOAD_LDS16(g, l)                                                     \
    __builtin_amdgcn_global_load_lds(                                         \
        (__attribute__((address_space(1))) void*)(g),                         \
        (__attribute__((address_space(3))) void*)(l), 16, 0, 0)

// ---------------------------------------------------------------------------
// cast fp32 -> fp16
// ---------------------------------------------------------------------------
__global__ __launch_bounds__(256) void cast_f32_f16_kernel(
    const float* __restrict__ in, _Float16* __restrict__ out, int n)
{
    const int i = (blockIdx.x * 256 + threadIdx.x) * 4;
    if (i + 3 < n) {
        float4 v = *(const float4*)(in + i);
        half4v h;
        h[0] = (_Float16)v.x; h[1] = (_Float16)v.y;
        h[2] = (_Float16)v.z; h[3] = (_Float16)v.w;
        *(half4v*)(out + i) = h;
    }
}

// ---------------------------------------------------------------------------
// transpose + cast: in[R][C] fp32 -> out[C][R] fp16
// ---------------------------------------------------------------------------
__global__ __launch_bounds__(256) void transpose_cast_kernel(
    const float* __restrict__ in, _Float16* __restrict__ out, int R, int C)
{
    __shared__ float tile[32][33];
    const int c0 = blockIdx.x * 32, r0 = blockIdx.y * 32;
    const int tx = threadIdx.x & 31, ty = threadIdx.x >> 5;
    #pragma unroll
    for (int q = 0; q < 4; ++q)
        tile[ty + 8 * q][tx] = in[(size_t)(r0 + ty + 8 * q) * C + c0 + tx];
    __syncthreads();
    #pragma unroll
    for (int q = 0; q < 4; ++q)
        out[(size_t)(c0 + ty + 8 * q) * R + r0 + tx] = (_Float16)tile[tx][ty + 8 * q];
}

// ---------------------------------------------------------------------------
// f16 MFMA GEMM (shared body): C = A[M][K] @ Bt[N][K]^T + bias
// 128x128 tile, BK=32, 4 waves, 4x4 16x16x32 MFMA/wave, global_load_lds.
// Two variants differ only in the epilogue store.
// ---------------------------------------------------------------------------
#define GEMM_BODY()                                                           \
    __shared__ __align__(16) _Float16 As[128 * 32];                           \
    __shared__ __align__(16) _Float16 Bs[128 * 32];                           \
    const int tid  = threadIdx.x;                                             \
    const int lane = tid & 63;                                                \
    const int w    = tid >> 6;                                                \
    const int wm   = (w >> 1) * 64;                                           \
    const int wn   = (w & 1) * 64;                                            \
    const int srow  = lane >> 2;                                              \
    const int skoff = (lane & 3) * 8;                                         \
    const _Float16* gA = A  + (size_t)(blockIdx.y * 128 + w * 32 + srow) * K + skoff; \
    const _Float16* gB = Bt + (size_t)(blockIdx.x * 128 + w * 32 + srow) * K + skoff; \
    _Float16* lA0 = &As[(w * 32 +  0) * 32];                                  \
    _Float16* lA1 = &As[(w * 32 + 16) * 32];                                  \
    _Float16* lB0 = &Bs[(w * 32 +  0) * 32];                                  \
    _Float16* lB1 = &Bs[(w * 32 + 16) * 32];                                  \
    f32x4 acc[4][4];                                                          \
    _Pragma("unroll")                                                         \
    for (int i = 0; i < 4; ++i)                                               \
        _Pragma("unroll")                                                     \
        for (int j = 0; j < 4; ++j)                                           \
            _Pragma("unroll")                                                 \
            for (int rr = 0; rr < 4; ++rr) acc[i][j][rr] = 0.f;               \
    const int fr = lane & 15;                                                 \
    const int fq = lane >> 4;                                                 \
    for (int k0 = 0; k0 < K; k0 += 32) {                                      \
        GLOAD_LDS16(gA + k0,                  lA0);                           \
        GLOAD_LDS16(gA + 16 * (size_t)K + k0, lA1);                           \
        GLOAD_LDS16(gB + k0,                  lB0);                           \
        GLOAD_LDS16(gB + 16 * (size_t)K + k0, lB1);                           \
        __syncthreads();                                                      \
        half8 af[4], bf[4];                                                   \
        _Pragma("unroll")                                                     \
        for (int i = 0; i < 4; ++i)                                           \
            af[i] = *(const half8*)&As[(wm + i * 16 + fr) * 32 + fq * 8];     \
        _Pragma("unroll")                                                     \
        for (int j = 0; j < 4; ++j)                                           \
            bf[j] = *(const half8*)&Bs[(wn + j * 16 + fr) * 32 + fq * 8];     \
        _Pragma("unroll")                                                     \
        for (int i = 0; i < 4; ++i)                                           \
            _Pragma("unroll")                                                 \
            for (int j = 0; j < 4; ++j)                                       \
                acc[i][j] = __builtin_amdgcn_mfma_f32_16x16x32_f16(           \
                    af[i], bf[j], acc[i][j], 0, 0, 0);                        \
        __syncthreads();                                                      \
    }

// plain row-major output (fp32 or fp16)
template <typename OutT>
__global__ __launch_bounds__(256) void gemm_bt_f16(
    const _Float16* __restrict__ A, const _Float16* __restrict__ Bt,
    const float* __restrict__ bias, OutT* __restrict__ C,
    int M, int N, int K)
{
    GEMM_BODY()
    #pragma unroll
    for (int j = 0; j < 4; ++j) {
        const int col = blockIdx.x * 128 + wn + j * 16 + fr;
        const float bv = bias[col];
        #pragma unroll
        for (int i = 0; i < 4; ++i) {
            const int row = blockIdx.y * 128 + wm + i * 16 + fq * 4;
            #pragma unroll
            for (int rr = 0; rr < 4; ++rr)
                C[(size_t)(row + rr) * N + col] = (OutT)(acc[i][j][rr] + bv);
        }
    }
}

// qkv head-major output: dst[b][h][which][t][e], f16
__global__ __launch_bounds__(256) void gemm_bt_f16_qkv(
    const _Float16* __restrict__ A, const _Float16* __restrict__ Bt,
    const float* __restrict__ bias, _Float16* __restrict__ C,
    int M, int N, int K)
{
    GEMM_BODY()
    #pragma unroll
    for (int j = 0; j < 4; ++j) {
        const int col = blockIdx.x * 128 + wn + j * 16 + fr;
        const float bv = bias[col];
        const int which = col >> 10;
        const int hh    = (col >> 6) & 15;
        const int e     = col & 63;
        #pragma unroll
        for (int i = 0; i < 4; ++i) {
            const int row = blockIdx.y * 128 + wm + i * 16 + fq * 4;
            #pragma unroll
            for (int rr = 0; rr < 4; ++rr) {
                const int rowr = row + rr;
                const int b2 = rowr >> 11, t = rowr & 2047;
                const size_t dst =
                    (((size_t)(b2 * 16 + hh) * 3 + which) * 2048 + t) * 64 + e;
                C[dst] = (_Float16)(acc[i][j][rr] + bv);
            }
        }
    }
}

// ---------------------------------------------------------------------------
// Barrier-free MFMA periodic-sparse attention.
// Block = (b,h, residue r, 64-query tile), longest-first. 4 waves; wave w
// independently processes k-tiles {w, w+4, ...} for ALL 64 queries with its
// own online softmax (no barriers). K fragments load straight from global
// (head-major rows are d-contiguous). V transposed in registers -> LDS.
// One barrier: merge partial (O,m,l) across waves.
// ---------------------------------------------------------------------------
__global__ __launch_bounds__(256, 2) void attn_mfma2_kernel(
    const _Float16* __restrict__ qkv, const int* __restrict__ periods,
    _Float16* __restrict__ ao)
{
    constexpr int LDK   = 72;
    constexpr int WSLOT = 2 * 64 * LDK;     // halves per wave slice (P + Vt)
    __shared__ __align__(16) _Float16 lds[4 * WSLOT];
    __shared__ float ml[4][64][2];

    const int bh = blockIdx.y;
    int p = periods[bh]; if (p < 1) p = 1;

    // blockIdx.x -> (residue r, q-tile), deepest tile first within residue
    int tidx = blockIdx.x;
    int r = -1, q0 = 0, nr = 0;
    for (int rr2 = 0; rr2 < p; ++rr2) {
        const int n  = (T_ - 1 - rr2) / p + 1;
        const int nt = (n + 63) >> 6;
        if (tidx < nt) { r = rr2; nr = n; q0 = (nt - 1 - tidx) << 6; break; }
        tidx -= nt;
    }
    if (r < 0) return;

    const int tid = threadIdx.x, lane = tid & 63, w = tid >> 6;
    const int ln = lane & 15, fq = lane >> 4;
    const int qn  = min(64, nr - q0);
    const int kts = (q0 + qn + 63) >> 6;

    _Float16* Ps  = lds + w * WSLOT;        // [64][LDK]  P (A-layout)
    _Float16* Vts = Ps + 64 * LDK;          // [64][LDK]  V^T [d][key]

    const size_t hs = (size_t)T_ * HD_;
    const _Float16* qb = qkv + (size_t)(bh * 3) * hs;
    const _Float16* kb = qb + hs;
    const _Float16* vb = kb + hs;

    // ---- Q A-fragments (all 64 q rows of this tile) ----
    half8 aq[4][2];
    #pragma unroll
    for (int mt = 0; mt < 4; ++mt) {
        const int qi = min(q0 + mt * 16 + ln, nr - 1);
        const _Float16* qrow = qb + (size_t)(r + qi * p) * HD_;
        aq[mt][0] = *(const half8*)(qrow + fq * 8);
        aq[mt][1] = *(const half8*)(qrow + 32 + fq * 8);
    }

    f32x4 Od[4][4];                 // [q-tile mt][d-tile nt], rr = q sub-row
    float m_i[4][4], l_i[4][4];     // [mt][rr]
    #pragma unroll
    for (int mt = 0; mt < 4; ++mt) {
        #pragma unroll
        for (int nt = 0; nt < 4; ++nt)
            #pragma unroll
            for (int rr = 0; rr < 4; ++rr) Od[mt][nt][rr] = 0.f;
        #pragma unroll
        for (int rr = 0; rr < 4; ++rr) { m_i[mt][rr] = -INFINITY; l_i[mt][rr] = 0.f; }
    }

    const int va  = lane & 15;          // V staging: keys 4va..4va+3
    const int vdb = (lane >> 4) * 16;   //            d range [vdb, vdb+16)

    for (int kt = w; kt < kts; kt += 4) {
        const int k0 = kt << 6;

        // ---- K fragments straight from global (B-layout: n=key, k=d) ----
        half8 bk[4][2];
        #pragma unroll
        for (int nt = 0; nt < 4; ++nt) {
            const int kj = min(k0 + nt * 16 + ln, nr - 1);
            const _Float16* krow = kb + (size_t)(r + kj * p) * HD_;
            bk[nt][0] = *(const half8*)(krow + fq * 8);
            bk[nt][1] = *(const half8*)(krow + 32 + fq * 8);
        }
        // ---- V rows issued now, consumed after softmax ----
        half8 vreg[4][2];
        #pragma unroll
        for (int c = 0; c < 4; ++c) {
            const int kj = min(k0 + va * 4 + c, nr - 1);
            const _Float16* vrow = vb + (size_t)(r + kj * p) * HD_ + vdb;
            vreg[c][0] = *(const half8*)(vrow);
            vreg[c][1] = *(const half8*)(vrow + 8);
        }

        const bool diag = (k0 + 64 > q0);

        // ---- S + online softmax + P, one 16-row q-tile at a time ----
        #pragma unroll
        for (int mt = 0; mt < 4; ++mt) {
            f32x4 Sd[4];
            #pragma unroll
            for (int nt = 0; nt < 4; ++nt) {
                #pragma unroll
                for (int rr = 0; rr < 4; ++rr) Sd[nt][rr] = 0.f;
                Sd[nt] = __builtin_amdgcn_mfma_f32_16x16x32_f16(aq[mt][0], bk[nt][0], Sd[nt], 0, 0, 0);
                Sd[nt] = __builtin_amdgcn_mfma_f32_16x16x32_f16(aq[mt][1], bk[nt][1], Sd[nt], 0, 0, 0);
            }
            #pragma unroll
            for (int rr = 0; rr < 4; ++rr) {
                const int q_abs = q0 + mt * 16 + fq * 4 + rr;
                float s0 = Sd[0][rr] * 0.125f, s1 = Sd[1][rr] * 0.125f;
                float s2 = Sd[2][rr] * 0.125f, s3 = Sd[3][rr] * 0.125f;
                if (diag) {
                    if (k0 +  0 + ln > q_abs) s0 = -INFINITY;
                    if (k0 + 16 + ln > q_abs) s1 = -INFINITY;
                    if (k0 + 32 + ln > q_abs) s2 = -INFINITY;
                    if (k0 + 48 + ln > q_abs) s3 = -INFINITY;
                }
                float mx = fmaxf(fmaxf(s0, s1), fmaxf(s2, s3));
                mx = fmaxf(mx, __shfl_xor(mx, 1));
                mx = fmaxf(mx, __shfl_xor(mx, 2));
                mx = fmaxf(mx, __shfl_xor(mx, 4));
                mx = fmaxf(mx, __shfl_xor(mx, 8));
                const float newm  = fmaxf(m_i[mt][rr], mx);
                const float alpha = (newm == -INFINITY) ? 0.f : __expf(m_i[mt][rr] - newm);
                m_i[mt][rr] = newm;
                float e0 = (newm == -INFINITY) ? 0.f : __expf(s0 - newm);
                float e1 = (newm == -INFINITY) ? 0.f : __expf(s1 - newm);
                float e2 = (newm == -INFINITY) ? 0.f : __expf(s2 - newm);
                float e3 = (newm == -INFINITY) ? 0.f : __expf(s3 - newm);
                float ls = e0 + e1 + e2 + e3;
                ls += __shfl_xor(ls, 1);
                ls += __shfl_xor(ls, 2);
                ls += __shfl_xor(ls, 4);
                ls += __shfl_xor(ls, 8);
                l_i[mt][rr] = l_i[mt][rr] * alpha + ls;
                #pragma unroll
                for (int nt = 0; nt < 4; ++nt) Od[mt][nt][rr] *= alpha;
                const int prow = (mt * 16 + fq * 4 + rr) * LDK;
                Ps[prow +  0 + ln] = (_Float16)e0;
                Ps[prow + 16 + ln] = (_Float16)e1;
                Ps[prow + 32 + ln] = (_Float16)e2;
                Ps[prow + 48 + ln] = (_Float16)e3;
            }
        }

        // ---- stage V^T (vreg has arrived during S/softmax) ----
        #pragma unroll
        for (int dd = 0; dd < 16; ++dd) {
            half4v t;
            #pragma unroll
            for (int c = 0; c < 4; ++c)
                t[c] = (dd < 8) ? vreg[c][0][dd] : vreg[c][1][dd - 8];
            *(half4v*)&Vts[(vdb + dd) * LDK + va * 4] = t;
        }

        // ---- O += P V  (DS ops are wave-ordered; no barrier needed) ----
        half8 bv[4][2];
        #pragma unroll
        for (int nt = 0; nt < 4; ++nt) {
            bv[nt][0] = *(const half8*)&Vts[(nt * 16 + ln) * LDK + fq * 8];
            bv[nt][1] = *(const half8*)&Vts[(nt * 16 + ln) * LDK + 32 + fq * 8];
        }
        #pragma unroll
        for (int mt = 0; mt < 4; ++mt) {
            half8 ap0 = *(const half8*)&Ps[(mt * 16 + ln) * LDK + fq * 8];
            half8 ap1 = *(const half8*)&Ps[(mt * 16 + ln) * LDK + 32 + fq * 8];
            #pragma unroll
            for (int nt = 0; nt < 4; ++nt) {
                Od[mt][nt] = __builtin_amdgcn_mfma_f32_16x16x32_f16(ap0, bv[nt][0], Od[mt][nt], 0, 0, 0);
                Od[mt][nt] = __builtin_amdgcn_mfma_f32_16x16x32_f16(ap1, bv[nt][1], Od[mt][nt], 0, 0, 0);
            }
        }
    }

    // ---- publish partials (reuse this wave's LDS slice) ----
    float* Opub = (float*)(lds + w * WSLOT);     // [64][64] f32 = 16 KB <= slice
    #pragma unroll
    for (int mt = 0; mt < 4; ++mt) {
        #pragma unroll
        for (int rr = 0; rr < 4; ++rr) {
            const int q = mt * 16 + fq * 4 + rr;
            #pragma unroll
            for (int nt = 0; nt < 4; ++nt)
                Opub[q * 64 + nt * 16 + ln] = Od[mt][nt][rr];
            if (ln == 0) {
                ml[w][q][0] = m_i[mt][rr];
                ml[w][q][1] = l_i[mt][rr];
            }
        }
    }
    __syncthreads();

    // ---- merge across waves; wave w owns q rows [w*16, w*16+16) ----
    const int bb = bh >> 4, hh = bh & 15;
    for (int qq = 0; qq < 16; ++qq) {
        const int q = w * 16 + qq;
        if (q >= qn) continue;
        float mstar = fmaxf(fmaxf(ml[0][q][0], ml[1][q][0]),
                            fmaxf(ml[2][q][0], ml[3][q][0]));
        float osum = 0.f, lsum = 0.f;
        #pragma unroll
        for (int v = 0; v < 4; ++v) {
            const float sc = __expf(ml[v][q][0] - mstar);
            lsum += sc * ml[v][q][1];
            osum += sc * ((const float*)(lds + v * WSLOT))[q * 64 + lane];
        }
        const int i = r + (q0 + q) * p;
        ao[((size_t)bb * T_ + i) * D_ + hh * HD_ + lane] = (_Float16)(osum / lsum);
    }
}

// ---------------------------------------------------------------------------
extern "C" void kernel_launch(void* const* d_in, const int* in_sizes, int n_in,
                              void* d_out, int out_size, void* d_ws, size_t ws_size,
                              hipStream_t stream)
{
    const float* x       = (const float*)d_in[0];
    const int*   periods = (const int*)  d_in[1];
    const float* w_qkv   = (const float*)d_in[2];
    const float* b_qkv   = (const float*)d_in[3];
    const float* w_out   = (const float*)d_in[4];
    const float* b_out   = (const float*)d_in[5];
    float*       out     = (float*)d_out;

    const int M = B_ * T_;                                  // 4096

    _Float16* x16   = (_Float16*)d_ws;                      // 8 MB
    _Float16* wqkvT = x16   + (size_t)M * D_;               // 6 MB  [3D][D]
    _Float16* qkv16 = wqkvT + (size_t)(3 * D_) * D_;        // 24 MB [b][h][3][T][64]
    _Float16* ao16  = qkv16 + (size_t)M * 3 * D_;           // 8 MB  [M][D]
    _Float16* woutT = ao16  + (size_t)M * D_;               // 2 MB  [D][D]

    cast_f32_f16_kernel<<<(M * D_) / (256 * 4), 256, 0, stream>>>(x, x16, M * D_);
    transpose_cast_kernel<<<dim3((3 * D_) / 32, D_ / 32), 256, 0, stream>>>(
        w_qkv, wqkvT, D_, 3 * D_);
    transpose_cast_kernel<<<dim3(D_ / 32, D_ / 32), 256, 0, stream>>>(
        w_out, woutT, D_, D_);

    // 1) qkv = x @ w_qkv + b_qkv  (f16 MFMA, head-major f16 out)
    gemm_bt_f16_qkv<<<dim3((3 * D_) / 128, M / 128), 256, 0, stream>>>(
        x16, wqkvT, b_qkv, qkv16, M, 3 * D_, D_);

    // 2) periodic sparse attention -> ao16 (barrier-free wave-split MFMA)
    attn_mfma2_kernel<<<dim3(48, B_ * H_), 256, 0, stream>>>(qkv16, periods, ao16);

    // 3) out = ao @ w_out + b_out  (f16 MFMA, fp32 out)
    gemm_bt_f16<float><<<dim3(D_ / 128, M / 128), 256, 0, stream>>>(
        ao16, woutT, b_out, out, M, D_, D_);
}

// Round 6
// 265.696 us; speedup vs baseline: 1.0018x; 1.0018x over previous
//
#include <hip/hip_runtime.h>
#include <math.h>

#define B_  2
#define T_  2048
#define D_  1024
#define H_  16
#define HD_ 64

typedef float    f32x4  __attribute__((ext_vector_type(4)));
typedef _Float16 half8  __attribute__((ext_vector_type(8)));
typedef _Float16 half4v __attribute__((ext_vector_type(4)));

#define GLOAD_LDS16(g, l)                                                     \
    __builtin_amdgcn_global_load_lds(                                         \
        (__attribute__((address_space(1))) void*)(g),                         \
        (__attribute__((address_space(3))) void*)(l), 16, 0, 0)

// ---------------------------------------------------------------------------
// cast fp32 -> fp16
// ---------------------------------------------------------------------------
__global__ __launch_bounds__(256) void cast_f32_f16_kernel(
    const float* __restrict__ in, _Float16* __restrict__ out, int n)
{
    const int i = (blockIdx.x * 256 + threadIdx.x) * 4;
    if (i + 3 < n) {
        float4 v = *(const float4*)(in + i);
        half4v h;
        h[0] = (_Float16)v.x; h[1] = (_Float16)v.y;
        h[2] = (_Float16)v.z; h[3] = (_Float16)v.w;
        *(half4v*)(out + i) = h;
    }
}

// ---------------------------------------------------------------------------
// transpose + cast: in[R][C] fp32 -> out[C][R] fp16
// ---------------------------------------------------------------------------
__global__ __launch_bounds__(256) void transpose_cast_kernel(
    const float* __restrict__ in, _Float16* __restrict__ out, int R, int C)
{
    __shared__ float tile[32][33];
    const int c0 = blockIdx.x * 32, r0 = blockIdx.y * 32;
    const int tx = threadIdx.x & 31, ty = threadIdx.x >> 5;
    #pragma unroll
    for (int q = 0; q < 4; ++q)
        tile[ty + 8 * q][tx] = in[(size_t)(r0 + ty + 8 * q) * C + c0 + tx];
    __syncthreads();
    #pragma unroll
    for (int q = 0; q < 4; ++q)
        out[(size_t)(c0 + ty + 8 * q) * R + r0 + tx] = (_Float16)tile[tx][ty + 8 * q];
}

// ---------------------------------------------------------------------------
// f16 MFMA GEMM (shared body): C = A[M][K] @ Bt[N][K]^T + bias
// 128x128 tile, BK=32, 4 waves, 4x4 16x16x32 MFMA/wave, global_load_lds.
// ---------------------------------------------------------------------------
#define GEMM_BODY()                                                           \
    __shared__ __align__(16) _Float16 As[128 * 32];                           \
    __shared__ __align__(16) _Float16 Bs[128 * 32];                           \
    const int tid  = threadIdx.x;                                             \
    const int lane = tid & 63;                                                \
    const int w    = tid >> 6;                                                \
    const int wm   = (w >> 1) * 64;                                           \
    const int wn   = (w & 1) * 64;                                            \
    const int srow  = lane >> 2;                                              \
    const int skoff = (lane & 3) * 8;                                         \
    const _Float16* gA = A  + (size_t)(blockIdx.y * 128 + w * 32 + srow) * K + skoff; \
    const _Float16* gB = Bt + (size_t)(blockIdx.x * 128 + w * 32 + srow) * K + skoff; \
    _Float16* lA0 = &As[(w * 32 +  0) * 32];                                  \
    _Float16* lA1 = &As[(w * 32 + 16) * 32];                                  \
    _Float16* lB0 = &Bs[(w * 32 +  0) * 32];                                  \
    _Float16* lB1 = &Bs[(w * 32 + 16) * 32];                                  \
    f32x4 acc[4][4];                                                          \
    _Pragma("unroll")                                                         \
    for (int i = 0; i < 4; ++i)                                               \
        _Pragma("unroll")                                                     \
        for (int j = 0; j < 4; ++j)                                           \
            _Pragma("unroll")                                                 \
            for (int rr = 0; rr < 4; ++rr) acc[i][j][rr] = 0.f;               \
    const int fr = lane & 15;                                                 \
    const int fq = lane >> 4;                                                 \
    for (int k0 = 0; k0 < K; k0 += 32) {                                      \
        GLOAD_LDS16(gA + k0,                  lA0);                           \
        GLOAD_LDS16(gA + 16 * (size_t)K + k0, lA1);                           \
        GLOAD_LDS16(gB + k0,                  lB0);                           \
        GLOAD_LDS16(gB + 16 * (size_t)K + k0, lB1);                           \
        __syncthreads();                                                      \
        half8 af[4], bf[4];                                                   \
        _Pragma("unroll")                                                     \
        for (int i = 0; i < 4; ++i)                                           \
            af[i] = *(const half8*)&As[(wm + i * 16 + fr) * 32 + fq * 8];     \
        _Pragma("unroll")                                                     \
        for (int j = 0; j < 4; ++j)                                           \
            bf[j] = *(const half8*)&Bs[(wn + j * 16 + fr) * 32 + fq * 8];     \
        _Pragma("unroll")                                                     \
        for (int i = 0; i < 4; ++i)                                           \
            _Pragma("unroll")                                                 \
            for (int j = 0; j < 4; ++j)                                       \
                acc[i][j] = __builtin_amdgcn_mfma_f32_16x16x32_f16(           \
                    af[i], bf[j], acc[i][j], 0, 0, 0);                        \
        __syncthreads();                                                      \
    }

// plain row-major output (fp32 or fp16)
template <typename OutT>
__global__ __launch_bounds__(256) void gemm_bt_f16(
    const _Float16* __restrict__ A, const _Float16* __restrict__ Bt,
    const float* __restrict__ bias, OutT* __restrict__ C,
    int M, int N, int K)
{
    GEMM_BODY()
    #pragma unroll
    for (int j = 0; j < 4; ++j) {
        const int col = blockIdx.x * 128 + wn + j * 16 + fr;
        const float bv = bias[col];
        #pragma unroll
        for (int i = 0; i < 4; ++i) {
            const int row = blockIdx.y * 128 + wm + i * 16 + fq * 4;
            #pragma unroll
            for (int rr = 0; rr < 4; ++rr)
                C[(size_t)(row + rr) * N + col] = (OutT)(acc[i][j][rr] + bv);
        }
    }
}

// qkv head-major output: dst[b][h][which][t][e], f16
__global__ __launch_bounds__(256) void gemm_bt_f16_qkv(
    const _Float16* __restrict__ A, const _Float16* __restrict__ Bt,
    const float* __restrict__ bias, _Float16* __restrict__ C,
    int M, int N, int K)
{
    GEMM_BODY()
    #pragma unroll
    for (int j = 0; j < 4; ++j) {
        const int col = blockIdx.x * 128 + wn + j * 16 + fr;
        const float bv = bias[col];
        const int which = col >> 10;
        const int hh    = (col >> 6) & 15;
        const int e     = col & 63;
        #pragma unroll
        for (int i = 0; i < 4; ++i) {
            const int row = blockIdx.y * 128 + wm + i * 16 + fq * 4;
            #pragma unroll
            for (int rr = 0; rr < 4; ++rr) {
                const int rowr = row + rr;
                const int b2 = rowr >> 11, t = rowr & 2047;
                const size_t dst =
                    (((size_t)(b2 * 16 + hh) * 3 + which) * 2048 + t) * 64 + e;
                C[dst] = (_Float16)(acc[i][j][rr] + bv);
            }
        }
    }
}

// ---------------------------------------------------------------------------
// MFMA periodic-sparse attention, R4 work split + latency fixes.
// Block = (b,h, residue r, 64-query tile), longest-first. Wave w owns q-rows
// [w*16, w*16+16). Per 64-key tile:
//   - K B-fragments straight from global (no LDS, no conflicts)
//   - V^T double-buffered in LDS; next tile's V prefetched into registers
//   - ONE barrier per iteration
//   - S = QK^T (8 MFMA), reg online softmax, P->LDS (wave-private), O += PV
// ---------------------------------------------------------------------------
__global__ __launch_bounds__(256, 4) void attn_mfma4_kernel(
    const _Float16* __restrict__ qkv, const int* __restrict__ periods,
    _Float16* __restrict__ ao)
{
    constexpr int LDK = 72;
    __shared__ __align__(16) _Float16 Vts[2][64 * LDK];   // V^T [d][key], dbuf
    __shared__ __align__(16) _Float16 Ps[64 * LDK];       // P, wave-private rows

    const int bh = blockIdx.y;
    int p = periods[bh]; if (p < 1) p = 1;

    // blockIdx.x -> (residue r, q-tile), deepest tile first
    int tidx = blockIdx.x;
    int r = -1, q0 = 0, nr = 0;
    for (int rr2 = 0; rr2 < p; ++rr2) {
        const int n  = (T_ - 1 - rr2) / p + 1;
        const int nt = (n + 63) >> 6;
        if (tidx < nt) { r = rr2; nr = n; q0 = (nt - 1 - tidx) << 6; break; }
        tidx -= nt;
    }
    if (r < 0) return;
    const int qn = min(64, nr - q0);

    const int tid = threadIdx.x, lane = tid & 63, w = tid >> 6;
    const int ln = lane & 15, fq = lane >> 4;
    const int kts = (q0 + qn + 63) >> 6;

    const size_t hs = (size_t)T_ * HD_;
    const _Float16* qb = qkv + (size_t)(bh * 3) * hs;
    const _Float16* kb = qb + hs;
    const _Float16* vb = kb + hs;

    // ---- Q A-fragments for this wave's 16 q-rows ----
    half8 aq0, aq1;
    {
        const int qi = min(q0 + w * 16 + ln, nr - 1);
        const _Float16* qrow = qb + (size_t)(r + qi * p) * HD_;
        aq0 = *(const half8*)(qrow + fq * 8);
        aq1 = *(const half8*)(qrow + 32 + fq * 8);
    }

    f32x4 Od[4];
    float m_i[4], l_i[4];
    #pragma unroll
    for (int nt = 0; nt < 4; ++nt)
        #pragma unroll
        for (int rr = 0; rr < 4; ++rr) Od[nt][rr] = 0.f;
    #pragma unroll
    for (int rr = 0; rr < 4; ++rr) { m_i[rr] = -INFINITY; l_i[rr] = 0.f; }

    // V staging role (cooperative, 256 thr): keys 4vk..4vk+3, d-rows 4vd4..+3
    const int vk = tid & 15, vd4 = (tid >> 4) * 4;

    // ---- preload V tile 0 into registers ----
    half4v vreg[4];
    #pragma unroll
    for (int c = 0; c < 4; ++c) {
        const int kj = min(4 * vk + c, nr - 1);
        vreg[c] = *(const half4v*)(vb + (size_t)(r + kj * p) * HD_ + vd4);
    }

    for (int kt = 0; kt < kts; ++kt) {
        const int k0  = kt << 6;
        const int buf = kt & 1;

        // ---- write V^T for current tile (from prefetched vreg) ----
        #pragma unroll
        for (int dd = 0; dd < 4; ++dd) {
            half4v t;
            #pragma unroll
            for (int c = 0; c < 4; ++c) t[c] = vreg[c][dd];
            *(half4v*)&Vts[buf][(vd4 + dd) * LDK + 4 * vk] = t;
        }

        // ---- K B-fragments straight from global ----
        half8 bk[4][2];
        #pragma unroll
        for (int nt = 0; nt < 4; ++nt) {
            const int kj = min(k0 + nt * 16 + ln, nr - 1);
            const _Float16* krow = kb + (size_t)(r + kj * p) * HD_;
            bk[nt][0] = *(const half8*)(krow + fq * 8);
            bk[nt][1] = *(const half8*)(krow + 32 + fq * 8);
        }

        __syncthreads();   // Vts[buf] visible to all waves

        // ---- prefetch NEXT V tile (full iteration of flight time) ----
        if (kt + 1 < kts) {
            const int k0n = (kt + 1) << 6;
            #pragma unroll
            for (int c = 0; c < 4; ++c) {
                const int kj = min(k0n + 4 * vk + c, nr - 1);
                vreg[c] = *(const half4v*)(vb + (size_t)(r + kj * p) * HD_ + vd4);
            }
        }

        // ---- S = Q K^T ----
        f32x4 Sd[4];
        #pragma unroll
        for (int nt = 0; nt < 4; ++nt) {
            #pragma unroll
            for (int rr = 0; rr < 4; ++rr) Sd[nt][rr] = 0.f;
            Sd[nt] = __builtin_amdgcn_mfma_f32_16x16x32_f16(aq0, bk[nt][0], Sd[nt], 0, 0, 0);
            Sd[nt] = __builtin_amdgcn_mfma_f32_16x16x32_f16(aq1, bk[nt][1], Sd[nt], 0, 0, 0);
        }

        // ---- scale + causal mask + online softmax + P ----
        const bool diag = (k0 + 64 > q0);
        #pragma unroll
        for (int rr = 0; rr < 4; ++rr) {
            const int q_abs = q0 + w * 16 + fq * 4 + rr;
            float s0 = Sd[0][rr] * 0.125f, s1 = Sd[1][rr] * 0.125f;
            float s2 = Sd[2][rr] * 0.125f, s3 = Sd[3][rr] * 0.125f;
            if (diag) {
                if (k0 +  0 + ln > q_abs) s0 = -INFINITY;
                if (k0 + 16 + ln > q_abs) s1 = -INFINITY;
                if (k0 + 32 + ln > q_abs) s2 = -INFINITY;
                if (k0 + 48 + ln > q_abs) s3 = -INFINITY;
            }
            float mx = fmaxf(fmaxf(s0, s1), fmaxf(s2, s3));
            mx = fmaxf(mx, __shfl_xor(mx, 1));
            mx = fmaxf(mx, __shfl_xor(mx, 2));
            mx = fmaxf(mx, __shfl_xor(mx, 4));
            mx = fmaxf(mx, __shfl_xor(mx, 8));
            const float newm  = fmaxf(m_i[rr], mx);
            const float alpha = (newm == -INFINITY) ? 0.f : __expf(m_i[rr] - newm);
            m_i[rr] = newm;
            float e0 = (newm == -INFINITY) ? 0.f : __expf(s0 - newm);
            float e1 = (newm == -INFINITY) ? 0.f : __expf(s1 - newm);
            float e2 = (newm == -INFINITY) ? 0.f : __expf(s2 - newm);
            float e3 = (newm == -INFINITY) ? 0.f : __expf(s3 - newm);
            float ls = e0 + e1 + e2 + e3;
            ls += __shfl_xor(ls, 1);
            ls += __shfl_xor(ls, 2);
            ls += __shfl_xor(ls, 4);
            ls += __shfl_xor(ls, 8);
            l_i[rr] = l_i[rr] * alpha + ls;
            #pragma unroll
            for (int nt = 0; nt < 4; ++nt) Od[nt][rr] *= alpha;
            const int prow = (w * 16 + fq * 4 + rr) * LDK;
            Ps[prow +  0 + ln] = (_Float16)e0;
            Ps[prow + 16 + ln] = (_Float16)e1;
            Ps[prow + 32 + ln] = (_Float16)e2;
            Ps[prow + 48 + ln] = (_Float16)e3;
        }

        // ---- O += P V  (Ps rows wave-private; DS wave-ordered) ----
        half8 ap0 = *(const half8*)&Ps[(w * 16 + ln) * LDK + fq * 8];
        half8 ap1 = *(const half8*)&Ps[(w * 16 + ln) * LDK + 32 + fq * 8];
        #pragma unroll
        for (int nt = 0; nt < 4; ++nt) {
            half8 bv0 = *(const half8*)&Vts[buf][(nt * 16 + ln) * LDK + fq * 8];
            half8 bv1 = *(const half8*)&Vts[buf][(nt * 16 + ln) * LDK + 32 + fq * 8];
            Od[nt] = __builtin_amdgcn_mfma_f32_16x16x32_f16(ap0, bv0, Od[nt], 0, 0, 0);
            Od[nt] = __builtin_amdgcn_mfma_f32_16x16x32_f16(ap1, bv1, Od[nt], 0, 0, 0);
        }
    }

    // ---- normalize + store: row q = w*16 + fq*4+rr, col d = nt*16+ln ----
    const int bb = bh >> 4, hh = bh & 15;
    #pragma unroll
    for (int rr = 0; rr < 4; ++rr) {
        const int qq = w * 16 + fq * 4 + rr;
        if (q0 + qq < nr) {
            const int i = r + (q0 + qq) * p;
            const float inv = 1.f / l_i[rr];
            _Float16* orow = ao + ((size_t)bb * T_ + i) * D_ + hh * HD_;
            #pragma unroll
            for (int nt = 0; nt < 4; ++nt)
                orow[nt * 16 + ln] = (_Float16)(Od[nt][rr] * inv);
        }
    }
}

// ---------------------------------------------------------------------------
extern "C" void kernel_launch(void* const* d_in, const int* in_sizes, int n_in,
                              void* d_out, int out_size, void* d_ws, size_t ws_size,
                              hipStream_t stream)
{
    const float* x       = (const float*)d_in[0];
    const int*   periods = (const int*)  d_in[1];
    const float* w_qkv   = (const float*)d_in[2];
    const float* b_qkv   = (const float*)d_in[3];
    const float* w_out   = (const float*)d_in[4];
    const float* b_out   = (const float*)d_in[5];
    float*       out     = (float*)d_out;

    const int M = B_ * T_;                                  // 4096

    _Float16* x16   = (_Float16*)d_ws;                      // 8 MB
    _Float16* wqkvT = x16   + (size_t)M * D_;               // 6 MB  [3D][D]
    _Float16* qkv16 = wqkvT + (size_t)(3 * D_) * D_;        // 24 MB [b][h][3][T][64]
    _Float16* ao16  = qkv16 + (size_t)M * 3 * D_;           // 8 MB  [M][D]
    _Float16* woutT = ao16  + (size_t)M * D_;               // 2 MB  [D][D]

    cast_f32_f16_kernel<<<(M * D_) / (256 * 4), 256, 0, stream>>>(x, x16, M * D_);
    transpose_cast_kernel<<<dim3((3 * D_) / 32, D_ / 32), 256, 0, stream>>>(
        w_qkv, wqkvT, D_, 3 * D_);
    transpose_cast_kernel<<<dim3(D_ / 32, D_ / 32), 256, 0, stream>>>(
        w_out, woutT, D_, D_);

    // 1) qkv = x @ w_qkv + b_qkv  (f16 MFMA, head-major f16 out)
    gemm_bt_f16_qkv<<<dim3((3 * D_) / 128, M / 128), 256, 0, stream>>>(
        x16, wqkvT, b_qkv, qkv16, M, 3 * D_, D_);

    // 2) periodic sparse attention -> ao16
    attn_mfma4_kernel<<<dim3(48, B_ * H_), 256, 0, stream>>>(qkv16, periods, ao16);

    // 3) out = ao @ w_out + b_out  (f16 MFMA, fp32 out)
    gemm_bt_f16<float><<<dim3(D_ / 128, M / 128), 256, 0, stream>>>(
        ao16, woutT, b_out, out, M, D_, D_);
}

// Round 7
// 260.714 us; speedup vs baseline: 1.0209x; 1.0191x over previous
//
#include <hip/hip_runtime.h>
#include <math.h>

#define B_  2
#define T_  2048
#define D_  1024
#define H_  16
#define HD_ 64

typedef float    f32x4  __attribute__((ext_vector_type(4)));
typedef _Float16 half8  __attribute__((ext_vector_type(8)));
typedef _Float16 half4v __attribute__((ext_vector_type(4)));

#define GLOAD_LDS16(g, l)                                                     \
    __builtin_amdgcn_global_load_lds(                                         \
        (__attribute__((address_space(1))) void*)(g),                         \
        (__attribute__((address_space(3))) void*)(l), 16, 0, 0)

// ---------------------------------------------------------------------------
// cast fp32 -> fp16
// ---------------------------------------------------------------------------
__global__ __launch_bounds__(256) void cast_f32_f16_kernel(
    const float* __restrict__ in, _Float16* __restrict__ out, int n)
{
    const int i = (blockIdx.x * 256 + threadIdx.x) * 4;
    if (i + 3 < n) {
        float4 v = *(const float4*)(in + i);
        half4v h;
        h[0] = (_Float16)v.x; h[1] = (_Float16)v.y;
        h[2] = (_Float16)v.z; h[3] = (_Float16)v.w;
        *(half4v*)(out + i) = h;
    }
}

// ---------------------------------------------------------------------------
// transpose + cast: in[R][C] fp32 -> out[C][R] fp16
// ---------------------------------------------------------------------------
__global__ __launch_bounds__(256) void transpose_cast_kernel(
    const float* __restrict__ in, _Float16* __restrict__ out, int R, int C)
{
    __shared__ float tile[32][33];
    const int c0 = blockIdx.x * 32, r0 = blockIdx.y * 32;
    const int tx = threadIdx.x & 31, ty = threadIdx.x >> 5;
    #pragma unroll
    for (int q = 0; q < 4; ++q)
        tile[ty + 8 * q][tx] = in[(size_t)(r0 + ty + 8 * q) * C + c0 + tx];
    __syncthreads();
    #pragma unroll
    for (int q = 0; q < 4; ++q)
        out[(size_t)(c0 + ty + 8 * q) * R + r0 + tx] = (_Float16)tile[tx][ty + 8 * q];
}

// ---------------------------------------------------------------------------
// f16 MFMA GEMM (shared body): C = A[M][K] @ Bt[N][K]^T + bias
// 128x128 tile, BK=32, 4 waves, 4x4 16x16x32 MFMA/wave, global_load_lds.
// ---------------------------------------------------------------------------
#define GEMM_BODY()                                                           \
    __shared__ __align__(16) _Float16 As[128 * 32];                           \
    __shared__ __align__(16) _Float16 Bs[128 * 32];                           \
    const int tid  = threadIdx.x;                                             \
    const int lane = tid & 63;                                                \
    const int w    = tid >> 6;                                                \
    const int wm   = (w >> 1) * 64;                                           \
    const int wn   = (w & 1) * 64;                                            \
    const int srow  = lane >> 2;                                              \
    const int skoff = (lane & 3) * 8;                                         \
    const _Float16* gA = A  + (size_t)(blockIdx.y * 128 + w * 32 + srow) * K + skoff; \
    const _Float16* gB = Bt + (size_t)(blockIdx.x * 128 + w * 32 + srow) * K + skoff; \
    _Float16* lA0 = &As[(w * 32 +  0) * 32];                                  \
    _Float16* lA1 = &As[(w * 32 + 16) * 32];                                  \
    _Float16* lB0 = &Bs[(w * 32 +  0) * 32];                                  \
    _Float16* lB1 = &Bs[(w * 32 + 16) * 32];                                  \
    f32x4 acc[4][4];                                                          \
    _Pragma("unroll")                                                         \
    for (int i = 0; i < 4; ++i)                                               \
        _Pragma("unroll")                                                     \
        for (int j = 0; j < 4; ++j)                                           \
            _Pragma("unroll")                                                 \
            for (int rr = 0; rr < 4; ++rr) acc[i][j][rr] = 0.f;               \
    const int fr = lane & 15;                                                 \
    const int fq = lane >> 4;                                                 \
    for (int k0 = 0; k0 < K; k0 += 32) {                                      \
        GLOAD_LDS16(gA + k0,                  lA0);                           \
        GLOAD_LDS16(gA + 16 * (size_t)K + k0, lA1);                           \
        GLOAD_LDS16(gB + k0,                  lB0);                           \
        GLOAD_LDS16(gB + 16 * (size_t)K + k0, lB1);                           \
        __syncthreads();                                                      \
        half8 af[4], bf[4];                                                   \
        _Pragma("unroll")                                                     \
        for (int i = 0; i < 4; ++i)                                           \
            af[i] = *(const half8*)&As[(wm + i * 16 + fr) * 32 + fq * 8];     \
        _Pragma("unroll")                                                     \
        for (int j = 0; j < 4; ++j)                                           \
            bf[j] = *(const half8*)&Bs[(wn + j * 16 + fr) * 32 + fq * 8];     \
        _Pragma("unroll")                                                     \
        for (int i = 0; i < 4; ++i)                                           \
            _Pragma("unroll")                                                 \
            for (int j = 0; j < 4; ++j)                                       \
                acc[i][j] = __builtin_amdgcn_mfma_f32_16x16x32_f16(           \
                    af[i], bf[j], acc[i][j], 0, 0, 0);                        \
        __syncthreads();                                                      \
    }

// plain row-major output (fp32 or fp16)
template <typename OutT>
__global__ __launch_bounds__(256) void gemm_bt_f16(
    const _Float16* __restrict__ A, const _Float16* __restrict__ Bt,
    const float* __restrict__ bias, OutT* __restrict__ C,
    int M, int N, int K)
{
    GEMM_BODY()
    #pragma unroll
    for (int j = 0; j < 4; ++j) {
        const int col = blockIdx.x * 128 + wn + j * 16 + fr;
        const float bv = bias[col];
        #pragma unroll
        for (int i = 0; i < 4; ++i) {
            const int row = blockIdx.y * 128 + wm + i * 16 + fq * 4;
            #pragma unroll
            for (int rr = 0; rr < 4; ++rr)
                C[(size_t)(row + rr) * N + col] = (OutT)(acc[i][j][rr] + bv);
        }
    }
}

// qkv head-major output: dst[b][h][which][t][e], f16
__global__ __launch_bounds__(256) void gemm_bt_f16_qkv(
    const _Float16* __restrict__ A, const _Float16* __restrict__ Bt,
    const float* __restrict__ bias, _Float16* __restrict__ C,
    int M, int N, int K)
{
    GEMM_BODY()
    #pragma unroll
    for (int j = 0; j < 4; ++j) {
        const int col = blockIdx.x * 128 + wn + j * 16 + fr;
        const float bv = bias[col];
        const int which = col >> 10;
        const int hh    = (col >> 6) & 15;
        const int e     = col & 63;
        #pragma unroll
        for (int i = 0; i < 4; ++i) {
            const int row = blockIdx.y * 128 + wm + i * 16 + fq * 4;
            #pragma unroll
            for (int rr = 0; rr < 4; ++rr) {
                const int rowr = row + rr;
                const int b2 = rowr >> 11, t = rowr & 2047;
                const size_t dst =
                    (((size_t)(b2 * 16 + hh) * 3 + which) * 2048 + t) * 64 + e;
                C[dst] = (_Float16)(acc[i][j][rr] + bv);
            }
        }
    }
}

// ---------------------------------------------------------------------------
// ZERO-BARRIER MFMA periodic-sparse attention.
// Block = (b,h, residue r, 64-query tile), longest-first. Wave w owns q-rows
// [w*16, w*16+16) x ALL keys. Each wave has a PRIVATE LDS slice for V^T and
// P, so every LDS dependency is intra-wave (DS ops are wave-ordered) -> the
// K-loop has NO __syncthreads, NO vmcnt drains; global loads stay in flight
// across iterations and waves never lockstep.
// ---------------------------------------------------------------------------
__global__ __launch_bounds__(256, 3) void attn_mfma5_kernel(
    const _Float16* __restrict__ qkv, const int* __restrict__ periods,
    _Float16* __restrict__ ao)
{
    constexpr int LDK   = 72;
    constexpr int VSLOT = 64 * LDK;      // per-wave V^T [d][key]
    constexpr int PSLOT = 16 * LDK;      // per-wave P   [q_local][key]
    __shared__ __align__(16) _Float16 VtsAll[4 * VSLOT];   // 36 KB
    __shared__ __align__(16) _Float16 PsAll [4 * PSLOT];   //  9 KB

    const int bh = blockIdx.y;
    int p = periods[bh]; if (p < 1) p = 1;

    // blockIdx.x -> (residue r, q-tile), deepest tile first
    int tidx = blockIdx.x;
    int r = -1, q0 = 0, nr = 0;
    for (int rr2 = 0; rr2 < p; ++rr2) {
        const int n  = (T_ - 1 - rr2) / p + 1;
        const int nt = (n + 63) >> 6;
        if (tidx < nt) { r = rr2; nr = n; q0 = (nt - 1 - tidx) << 6; break; }
        tidx -= nt;
    }
    if (r < 0) return;
    const int qn = min(64, nr - q0);

    const int tid = threadIdx.x, lane = tid & 63, w = tid >> 6;
    const int ln = lane & 15, fq = lane >> 4;
    const int kts = (q0 + qn + 63) >> 6;

    _Float16* Vts = VtsAll + w * VSLOT;
    _Float16* Ps  = PsAll  + w * PSLOT;

    const size_t hs = (size_t)T_ * HD_;
    const _Float16* qb = qkv + (size_t)(bh * 3) * hs;
    const _Float16* kb = qb + hs;
    const _Float16* vb = kb + hs;

    // ---- Q A-fragments for this wave's 16 q-rows ----
    half8 aq0, aq1;
    {
        const int qi = min(q0 + w * 16 + ln, nr - 1);
        const _Float16* qrow = qb + (size_t)(r + qi * p) * HD_;
        aq0 = *(const half8*)(qrow + fq * 8);
        aq1 = *(const half8*)(qrow + 32 + fq * 8);
    }

    f32x4 Od[4];
    float m_i[4], l_i[4];
    #pragma unroll
    for (int nt = 0; nt < 4; ++nt)
        #pragma unroll
        for (int rr = 0; rr < 4; ++rr) Od[nt][rr] = 0.f;
    #pragma unroll
    for (int rr = 0; rr < 4; ++rr) { m_i[rr] = -INFINITY; l_i[rr] = 0.f; }

    // per-wave V staging role: lane covers keys 4vk..4vk+3, d in [vd, vd+16)
    const int vk = lane & 15, vd = (lane >> 4) * 16;

    for (int kt = 0; kt < kts; ++kt) {
        const int k0 = kt << 6;

        // ---- issue V loads (consumed after ~2 instr groups) ----
        half8 vreg[4][2];
        #pragma unroll
        for (int c = 0; c < 4; ++c) {
            const int kj = min(k0 + 4 * vk + c, nr - 1);
            const _Float16* vrow = vb + (size_t)(r + kj * p) * HD_ + vd;
            vreg[c][0] = *(const half8*)(vrow);
            vreg[c][1] = *(const half8*)(vrow + 8);
        }
        // ---- issue K loads (consumed at S, after V transpose) ----
        half8 bk[4][2];
        #pragma unroll
        for (int nt = 0; nt < 4; ++nt) {
            const int kj = min(k0 + nt * 16 + ln, nr - 1);
            const _Float16* krow = kb + (size_t)(r + kj * p) * HD_;
            bk[nt][0] = *(const half8*)(krow + fq * 8);
            bk[nt][1] = *(const half8*)(krow + 32 + fq * 8);
        }

        // ---- transpose-write V^T into this wave's slice (no barrier) ----
        #pragma unroll
        for (int dd = 0; dd < 16; ++dd) {
            half4v t;
            #pragma unroll
            for (int c = 0; c < 4; ++c)
                t[c] = (dd < 8) ? vreg[c][0][dd] : vreg[c][1][dd - 8];
            *(half4v*)&Vts[(vd + dd) * LDK + 4 * vk] = t;
        }

        // ---- S = Q K^T ----
        f32x4 Sd[4];
        #pragma unroll
        for (int nt = 0; nt < 4; ++nt) {
            #pragma unroll
            for (int rr = 0; rr < 4; ++rr) Sd[nt][rr] = 0.f;
            Sd[nt] = __builtin_amdgcn_mfma_f32_16x16x32_f16(aq0, bk[nt][0], Sd[nt], 0, 0, 0);
            Sd[nt] = __builtin_amdgcn_mfma_f32_16x16x32_f16(aq1, bk[nt][1], Sd[nt], 0, 0, 0);
        }

        // ---- scale + causal mask + online softmax + P (wave-private) ----
        const bool diag = (k0 + 64 > q0);
        #pragma unroll
        for (int rr = 0; rr < 4; ++rr) {
            const int q_abs = q0 + w * 16 + fq * 4 + rr;
            float s0 = Sd[0][rr] * 0.125f, s1 = Sd[1][rr] * 0.125f;
            float s2 = Sd[2][rr] * 0.125f, s3 = Sd[3][rr] * 0.125f;
            if (diag) {
                if (k0 +  0 + ln > q_abs) s0 = -INFINITY;
                if (k0 + 16 + ln > q_abs) s1 = -INFINITY;
                if (k0 + 32 + ln > q_abs) s2 = -INFINITY;
                if (k0 + 48 + ln > q_abs) s3 = -INFINITY;
            }
            float mx = fmaxf(fmaxf(s0, s1), fmaxf(s2, s3));
            mx = fmaxf(mx, __shfl_xor(mx, 1));
            mx = fmaxf(mx, __shfl_xor(mx, 2));
            mx = fmaxf(mx, __shfl_xor(mx, 4));
            mx = fmaxf(mx, __shfl_xor(mx, 8));
            const float newm  = fmaxf(m_i[rr], mx);
            const float alpha = (newm == -INFINITY) ? 0.f : __expf(m_i[rr] - newm);
            m_i[rr] = newm;
            float e0 = (newm == -INFINITY) ? 0.f : __expf(s0 - newm);
            float e1 = (newm == -INFINITY) ? 0.f : __expf(s1 - newm);
            float e2 = (newm == -INFINITY) ? 0.f : __expf(s2 - newm);
            float e3 = (newm == -INFINITY) ? 0.f : __expf(s3 - newm);
            float ls = e0 + e1 + e2 + e3;
            ls += __shfl_xor(ls, 1);
            ls += __shfl_xor(ls, 2);
            ls += __shfl_xor(ls, 4);
            ls += __shfl_xor(ls, 8);
            l_i[rr] = l_i[rr] * alpha + ls;
            #pragma unroll
            for (int nt = 0; nt < 4; ++nt) Od[nt][rr] *= alpha;
            const int prow = (fq * 4 + rr) * LDK;     // wave-local q row
            Ps[prow +  0 + ln] = (_Float16)e0;
            Ps[prow + 16 + ln] = (_Float16)e1;
            Ps[prow + 32 + ln] = (_Float16)e2;
            Ps[prow + 48 + ln] = (_Float16)e3;
        }

        // ---- O += P V  (all intra-wave LDS deps; DS wave-ordered) ----
        half8 ap0 = *(const half8*)&Ps[ln * LDK + fq * 8];
        half8 ap1 = *(const half8*)&Ps[ln * LDK + 32 + fq * 8];
        #pragma unroll
        for (int nt = 0; nt < 4; ++nt) {
            half8 bv0 = *(const half8*)&Vts[(nt * 16 + ln) * LDK + fq * 8];
            half8 bv1 = *(const half8*)&Vts[(nt * 16 + ln) * LDK + 32 + fq * 8];
            Od[nt] = __builtin_amdgcn_mfma_f32_16x16x32_f16(ap0, bv0, Od[nt], 0, 0, 0);
            Od[nt] = __builtin_amdgcn_mfma_f32_16x16x32_f16(ap1, bv1, Od[nt], 0, 0, 0);
        }
    }

    // ---- normalize + store: row q = w*16 + fq*4+rr, col d = nt*16+ln ----
    const int bb = bh >> 4, hh = bh & 15;
    #pragma unroll
    for (int rr = 0; rr < 4; ++rr) {
        const int qq = w * 16 + fq * 4 + rr;
        if (q0 + qq < nr) {
            const int i = r + (q0 + qq) * p;
            const float inv = 1.f / l_i[rr];
            _Float16* orow = ao + ((size_t)bb * T_ + i) * D_ + hh * HD_;
            #pragma unroll
            for (int nt = 0; nt < 4; ++nt)
                orow[nt * 16 + ln] = (_Float16)(Od[nt][rr] * inv);
        }
    }
}

// ---------------------------------------------------------------------------
extern "C" void kernel_launch(void* const* d_in, const int* in_sizes, int n_in,
                              void* d_out, int out_size, void* d_ws, size_t ws_size,
                              hipStream_t stream)
{
    const float* x       = (const float*)d_in[0];
    const int*   periods = (const int*)  d_in[1];
    const float* w_qkv   = (const float*)d_in[2];
    const float* b_qkv   = (const float*)d_in[3];
    const float* w_out   = (const float*)d_in[4];
    const float* b_out   = (const float*)d_in[5];
    float*       out     = (float*)d_out;

    const int M = B_ * T_;                                  // 4096

    _Float16* x16   = (_Float16*)d_ws;                      // 8 MB
    _Float16* wqkvT = x16   + (size_t)M * D_;               // 6 MB  [3D][D]
    _Float16* qkv16 = wqkvT + (size_t)(3 * D_) * D_;        // 24 MB [b][h][3][T][64]
    _Float16* ao16  = qkv16 + (size_t)M * 3 * D_;           // 8 MB  [M][D]
    _Float16* woutT = ao16  + (size_t)M * D_;               // 2 MB  [D][D]

    cast_f32_f16_kernel<<<(M * D_) / (256 * 4), 256, 0, stream>>>(x, x16, M * D_);
    transpose_cast_kernel<<<dim3((3 * D_) / 32, D_ / 32), 256, 0, stream>>>(
        w_qkv, wqkvT, D_, 3 * D_);
    transpose_cast_kernel<<<dim3(D_ / 32, D_ / 32), 256, 0, stream>>>(
        w_out, woutT, D_, D_);

    // 1) qkv = x @ w_qkv + b_qkv  (f16 MFMA, head-major f16 out)
    gemm_bt_f16_qkv<<<dim3((3 * D_) / 128, M / 128), 256, 0, stream>>>(
        x16, wqkvT, b_qkv, qkv16, M, 3 * D_, D_);

    // 2) periodic sparse attention -> ao16 (zero-barrier wave-private MFMA)
    attn_mfma5_kernel<<<dim3(48, B_ * H_), 256, 0, stream>>>(qkv16, periods, ao16);

    // 3) out = ao @ w_out + b_out  (f16 MFMA, fp32 out)
    gemm_bt_f16<float><<<dim3(D_ / 128, M / 128), 256, 0, stream>>>(
        ao16, woutT, b_out, out, M, D_, D_);
}